// Round 6
// baseline (261.595 us; speedup 1.0000x reference)
//
#include <hip/hip_runtime.h>
#include <hip/hip_bf16.h>

#define F      128
#define NROWS  2048
#define MROWS  2048
#define BN     128         // n-rows per pair block
#define BM     128         // m-cols per pair block
#define MT     (MROWS/BM)  // 16 m-tiles
#define GC     16          // g-chunk
#define NCH    (F/GC)      // 8 chunks
#define LW     36          // fused LDS row: 16 plane0 + 16 plane1 + 4 pad (conflict-free Latin quads)
#define LOG2E  1.44269504088896340736f

typedef float f32x2 __attribute__((ext_vector_type(2)));
typedef float f32x4 __attribute__((ext_vector_type(4)));

__device__ __forceinline__ f32x2 lo2(f32x4 v) { return __builtin_shufflevector(v, v, 0, 1); }
__device__ __forceinline__ f32x2 hi2(f32x4 v) { return __builtin_shufflevector(v, v, 2, 3); }
__device__ __forceinline__ f32x2 pk_add(f32x2 a, f32x2 b) {
    f32x2 d; asm("v_pk_add_f32 %0, %1, %2" : "=v"(d) : "v"(a), "v"(b)); return d;
}
__device__ __forceinline__ f32x2 pk_mul(f32x2 a, f32x2 b) {
    f32x2 d; asm("v_pk_mul_f32 %0, %1, %2" : "=v"(d) : "v"(a), "v"(b)); return d;
}

// --- Kernel 1: projections + ELU/w2 precompute + w2sum ----------------------
// a = (embeds@W1)[n][g], b = (base@W1)[m][g], w = w2[g]
// A1W = (a+1)*w   AEW = exp(a)*w   B1W = -b*w   BE = exp(-b)
// w*elu(a-b) + w = med3(A1W + B1W, AEW*BE, w)
__global__ __launch_bounds__(256) void proj_kernel(
    const float* __restrict__ embeds, const float* __restrict__ base,
    const float* __restrict__ W1, const float* __restrict__ w2,
    float* __restrict__ A1W, float* __restrict__ AEW,
    float* __restrict__ B1W, float* __restrict__ BEp,
    float* __restrict__ w2sum)
{
    const int tid = threadIdx.x;
    const int sub = tid >> 7;
    const int g   = tid & 127;
    const int row = blockIdx.x * 2 + sub;

    __shared__ float xs[2][F];
    {
        const float* src = (row < NROWS) ? &embeds[(size_t)row * F]
                                         : &base[(size_t)(row - NROWS) * F];
        xs[sub][g] = src[g];
    }
    __syncthreads();

    float acc = 0.0f;
#pragma unroll 8
    for (int f = 0; f < F; ++f)
        acc = fmaf(xs[sub][f], W1[f * F + g], acc);

    const float w = w2[g];
    if (row < NROWS) {
        const size_t idx = (size_t)row * F + g;
        A1W[idx] = (acc + 1.0f) * w;
        AEW[idx] = __builtin_amdgcn_exp2f(acc * LOG2E) * w;
    } else {
        const size_t idx = (size_t)(row - NROWS) * F + g;
        B1W[idx] = -acc * w;
        BEp[idx] = __builtin_amdgcn_exp2f(-acc * LOG2E);
    }

    if (blockIdx.x == 0 && tid < 64) {
        float s = w2[tid] + w2[tid + 64];
#pragma unroll
        for (int k = 1; k < 64; k <<= 1) s += __shfl_xor(s, k);
        if (tid == 0) *w2sum = s;
    }
}

// --- Kernel 2: pair kernel -----------------------------------------------------
// grid (16,16), 256 threads; tile 128x128; tr=tid>>4, tc=tid&15; Rn=Rm=8.
// rows n = n0 + tr + 16i, cols m = m0 + tc + 16j.
// LDS rows fused: [plane0 g0..15 | plane1 g0..15 | pad4], stride 36 floats.
// Double-buffered, reg-staged (T14), one barrier per chunk.
__global__ __launch_bounds__(256) void pair_kernel(
    const float* __restrict__ A1W, const float* __restrict__ AEW,
    const float* __restrict__ B1W, const float* __restrict__ BEp,
    const float* __restrict__ w2, const float* __restrict__ w2sum_p,
    const float* __restrict__ brew, float* __restrict__ partials)
{
    __shared__ float sA[2][BN][LW];
    __shared__ float sB[2][BM][LW];

    const int tid = threadIdx.x;
    const int nt  = blockIdx.x;
    const int mt  = blockIdx.y;
    const int n0  = nt * BN;
    const int m0  = mt * BM;
    const int tr  = tid >> 4;
    const int tc  = tid & 15;

    float acc[8][8];
#pragma unroll
    for (int i = 0; i < 8; ++i)
#pragma unroll
        for (int j = 0; j < 8; ++j) acc[i][j] = 0.0f;

    f32x4 rA[4], rB[4];

    // staging: idx = rnd*256+tid; r = idx>>3 (0..127), c4 = idx&7 (8 lanes/row)
    // c4<4 -> plane0 cols (c4&3)*4 ; c4>=4 -> plane1 ; LDS col = c4*4
#define LOADCH(G0)                                                             \
    { _Pragma("unroll")                                                        \
      for (int rnd = 0; rnd < 4; ++rnd) {                                      \
          const int idx = rnd * 256 + tid;                                     \
          const int r = idx >> 3, c4 = idx & 7;                                \
          const float* sa = (c4 < 4) ? A1W : AEW;                              \
          const float* sb = (c4 < 4) ? B1W : BEp;                              \
          const int col = (G0) + (c4 & 3) * 4;                                 \
          rA[rnd] = *(const f32x4*)&sa[(size_t)(n0 + r) * F + col];            \
          rB[rnd] = *(const f32x4*)&sb[(size_t)(m0 + r) * F + col];            \
      } }

#define WRITECH(BUF)                                                           \
    { _Pragma("unroll")                                                        \
      for (int rnd = 0; rnd < 4; ++rnd) {                                      \
          const int idx = rnd * 256 + tid;                                     \
          const int r = idx >> 3, c4 = idx & 7;                                \
          *(f32x4*)&sA[BUF][r][c4 * 4] = rA[rnd];                              \
          *(f32x4*)&sB[BUF][r][c4 * 4] = rB[rnd];                              \
      } }

    LOADCH(0)
    WRITECH(0)
    __syncthreads();

#pragma unroll 1
    for (int ch = 0; ch < NCH; ++ch) {
        const int g0  = ch * GC;
        const int buf = ch & 1;

        if (ch + 1 < NCH) LOADCH(g0 + GC)   // async-issue next chunk's globals

#pragma unroll
        for (int g4 = 0; g4 < GC; g4 += 4) {
            const f32x4 wq = *(const f32x4*)&w2[g0 + g4];
            f32x4 b1v[8], bev[8];
#pragma unroll
            for (int j = 0; j < 8; ++j) {
                b1v[j] = *(const f32x4*)&sB[buf][tc + 16 * j][g4];
                bev[j] = *(const f32x4*)&sB[buf][tc + 16 * j][16 + g4];
            }
#pragma unroll
            for (int i = 0; i < 8; ++i) {
                const f32x4 a1 = *(const f32x4*)&sA[buf][tr + 16 * i][g4];
                const f32x4 ae = *(const f32x4*)&sA[buf][tr + 16 * i][16 + g4];
                const f32x2 a1l = lo2(a1), a1h = hi2(a1);
                const f32x2 ael = lo2(ae), aeh = hi2(ae);
#pragma unroll
                for (int j = 0; j < 8; ++j) {
                    const f32x2 x1l = pk_add(a1l, lo2(b1v[j]));
                    const f32x2 eel = pk_mul(ael, lo2(bev[j]));
                    const f32x2 x1h = pk_add(a1h, hi2(b1v[j]));
                    const f32x2 eeh = pk_mul(aeh, hi2(bev[j]));
                    f32x2 s1, s2;
                    s1.x = __builtin_amdgcn_fmed3f(x1l.x, eel.x, wq.x);
                    s1.y = __builtin_amdgcn_fmed3f(x1l.y, eel.y, wq.y);
                    s2.x = __builtin_amdgcn_fmed3f(x1h.x, eeh.x, wq.z);
                    s2.y = __builtin_amdgcn_fmed3f(x1h.y, eeh.y, wq.w);
                    const f32x2 t = pk_add(s1, s2);
                    acc[i][j] += t.x + t.y;
                }
            }
        }

        if (ch + 1 < NCH) WRITECH((ch + 1) & 1)
        __syncthreads();
    }
#undef LOADCH
#undef WRITECH

    const float w2sum = *w2sum_p;
    float rsv[8];
#pragma unroll
    for (int j = 0; j < 8; ++j) rsv[j] = brew[m0 + tc + 16 * j];

#pragma unroll
    for (int i = 0; i < 8; ++i) {
        float sw = 0.0f, swr = 0.0f;
#pragma unroll
        for (int j = 0; j < 8; ++j) {
            const float dist = fabsf(acc[i][j] - w2sum);
            const float w = 1.0f / (dist + 1e-4f);
            sw += w;
            swr = fmaf(w, rsv[j], swr);
        }
#pragma unroll
        for (int k = 1; k < 16; k <<= 1) {   // reduce over tc (low 4 lane bits)
            sw  += __shfl_xor(sw, k);
            swr += __shfl_xor(swr, k);
        }
        if (tc == 0) {
            const int n = n0 + tr + 16 * i;
            partials[((size_t)n * MT + mt) * 2 + 0] = sw;
            partials[((size_t)n * MT + mt) * 2 + 1] = swr;
        }
    }
}

// --- Kernel 3: reduce tile partials, divide ------------------------------------
__global__ __launch_bounds__(256) void finalize_kernel(
    const float* __restrict__ partials, float* __restrict__ out)
{
    const int n = blockIdx.x * 256 + threadIdx.x;
    if (n < NROWS) {
        float sw = 0.0f, swr = 0.0f;
#pragma unroll
        for (int t = 0; t < MT; ++t) {
            sw  += partials[((size_t)n * MT + t) * 2 + 0];
            swr += partials[((size_t)n * MT + t) * 2 + 1];
        }
        out[n] = swr / sw;
    }
}

extern "C" void kernel_launch(void* const* d_in, const int* in_sizes, int n_in,
                              void* d_out, int out_size, void* d_ws, size_t ws_size,
                              hipStream_t stream)
{
    const float* embeds       = (const float*)d_in[0];  // [2048,128]
    const float* base_embeds  = (const float*)d_in[1];  // [2048,128]
    const float* base_rewards = (const float*)d_in[2];  // [2048]
    const float* W1           = (const float*)d_in[3];  // [128,128] (in,out)
    const float* w2           = (const float*)d_in[4];  // [128,1]
    float* out = (float*)d_out;

    // ws: partials [2048*MT*2] | A1W | AEW | B1W | BE (each 2048*128) | w2sum[1]
    float* partials = (float*)d_ws;
    float* A1W = partials + (size_t)NROWS * MT * 2;
    float* AEW = A1W + (size_t)NROWS * F;
    float* B1W = AEW + (size_t)NROWS * F;
    float* BEp = B1W + (size_t)MROWS * F;
    float* w2s = BEp + (size_t)MROWS * F;

    proj_kernel<<<(NROWS + MROWS) / 2, 256, 0, stream>>>(
        embeds, base_embeds, W1, w2, A1W, AEW, B1W, BEp, w2s);

    dim3 grid2(NROWS / BN, MROWS / BM);
    pair_kernel<<<grid2, 256, 0, stream>>>(A1W, AEW, B1W, BEp, w2, w2s, base_rewards, partials);

    finalize_kernel<<<(NROWS + 255) / 256, 256, 0, stream>>>(partials, out);
}

// Round 7
// 111.997 us; speedup vs baseline: 2.3357x; 2.3357x over previous
//
#include <hip/hip_runtime.h>
#include <hip/hip_bf16.h>

#define F      128
#define NROWS  2048
#define MROWS  2048
#define BN     128         // n-rows per pair block
#define BM     64          // m-cols per pair block
#define MT     (MROWS/BM)  // 32 m-tiles
#define GC     16          // g-chunk
#define NCH    (F/GC)      // 8 chunks
#define LW     36          // fused LDS row: 16 plane0 | 16 plane1 | 4 pad (conflict-free, measured R4/R6)
#define LOG2E  1.44269504088896340736f

typedef float f32x4 __attribute__((ext_vector_type(4)));

// --- Kernel 1: projections + ELU/w2 precompute + w2sum ----------------------
// a = (embeds@W1)[n][g], b = (base@W1)[m][g], w = w2[g]
// A1W = (a+1)*w   AEW = exp(a)*w   B1W = -b*w   BE = exp(-b)
// w*elu(a-b) + w = med3(A1W + B1W, AEW*BE, w)
__global__ __launch_bounds__(256) void proj_kernel(
    const float* __restrict__ embeds, const float* __restrict__ base,
    const float* __restrict__ W1, const float* __restrict__ w2,
    float* __restrict__ A1W, float* __restrict__ AEW,
    float* __restrict__ B1W, float* __restrict__ BEp,
    float* __restrict__ w2sum)
{
    const int tid = threadIdx.x;
    const int sub = tid >> 7;
    const int g   = tid & 127;
    const int row = blockIdx.x * 2 + sub;

    __shared__ float xs[2][F];
    {
        const float* src = (row < NROWS) ? &embeds[(size_t)row * F]
                                         : &base[(size_t)(row - NROWS) * F];
        xs[sub][g] = src[g];
    }
    __syncthreads();

    float acc = 0.0f;
#pragma unroll 8
    for (int f = 0; f < F; ++f)
        acc = fmaf(xs[sub][f], W1[f * F + g], acc);

    const float w = w2[g];
    if (row < NROWS) {
        const size_t idx = (size_t)row * F + g;
        A1W[idx] = (acc + 1.0f) * w;
        AEW[idx] = __builtin_amdgcn_exp2f(acc * LOG2E) * w;
    } else {
        const size_t idx = (size_t)(row - NROWS) * F + g;
        B1W[idx] = -acc * w;
        BEp[idx] = __builtin_amdgcn_exp2f(-acc * LOG2E);
    }

    if (blockIdx.x == 0 && tid < 64) {
        float s = w2[tid] + w2[tid + 64];
#pragma unroll
        for (int k = 1; k < 64; k <<= 1) s += __shfl_xor(s, k);
        if (tid == 0) *w2sum = s;
    }
}

// --- Kernel 2: pair kernel -----------------------------------------------------
// grid (16,32), 256 threads; tile 128(n)x64(m); tr=tid>>4 (16), tc=tid&15 (16).
// Thread owns rows n = n0 + tr + 16i (i<8), cols m = m0 + tc + 16j (j<4).
// LDS rows fused [p0 g0..15 | p1 g0..15 | pad4], stride 36; double-buffered.
// Pipeline per chunk: issue next-chunk globals -> compute -> write next buf -> barrier.
__global__ __launch_bounds__(256) void pair_kernel(
    const float* __restrict__ A1W, const float* __restrict__ AEW,
    const float* __restrict__ B1W, const float* __restrict__ BEp,
    const float* __restrict__ w2, const float* __restrict__ w2sum_p,
    const float* __restrict__ brew, float* __restrict__ partials)
{
    __shared__ float sA[2][BN][LW];   // 2*128*36*4 = 36.9 KB
    __shared__ float sB[2][BM][LW];   // 2*64*36*4  = 18.4 KB

    const int tid = threadIdx.x;
    const int nt  = blockIdx.x;
    const int mt  = blockIdx.y;
    const int n0  = nt * BN;
    const int m0  = mt * BM;
    const int tr  = tid >> 4;
    const int tc  = tid & 15;

    float acc[8][4];
#pragma unroll
    for (int i = 0; i < 8; ++i)
#pragma unroll
        for (int j = 0; j < 4; ++j) acc[i][j] = 0.0f;

    f32x4 st[6];

    // staging map: 1536 f32x4 per chunk = 6 rounds x 256 threads.
    // rounds 0..3: A rows (idx>>3 in 0..127); rounds 4..5: B rows (0..63).
    // c4 = idx&7: c4<4 -> plane0 (A1W/B1W), c4>=4 -> plane1 (AEW/BEp).
#define LOAD_STAGE(G0)                                                          \
    { _Pragma("unroll")                                                         \
      for (int rnd = 0; rnd < 6; ++rnd) {                                       \
          const int idx = rnd * 256 + tid;                                      \
          const int c4  = idx & 7;                                              \
          const int col = (G0) + (c4 & 3) * 4;                                  \
          if (rnd < 4) {                                                        \
              const int r = idx >> 3;                                           \
              const float* src = (c4 < 4) ? A1W : AEW;                          \
              st[rnd] = *(const f32x4*)&src[(size_t)(n0 + r) * F + col];        \
          } else {                                                              \
              const int r = (idx - 1024) >> 3;                                  \
              const float* src = (c4 < 4) ? B1W : BEp;                          \
              st[rnd] = *(const f32x4*)&src[(size_t)(m0 + r) * F + col];        \
          }                                                                     \
      } }

#define WRITE_STAGE(BUF)                                                        \
    { _Pragma("unroll")                                                         \
      for (int rnd = 0; rnd < 6; ++rnd) {                                       \
          const int idx = rnd * 256 + tid;                                      \
          const int c4  = idx & 7;                                              \
          if (rnd < 4) {                                                        \
              const int r = idx >> 3;                                           \
              *(f32x4*)&sA[BUF][r][c4 * 4] = st[rnd];                           \
          } else {                                                              \
              const int r = (idx - 1024) >> 3;                                  \
              *(f32x4*)&sB[BUF][r][c4 * 4] = st[rnd];                           \
          }                                                                     \
      } }

    LOAD_STAGE(0)
    WRITE_STAGE(0)
    __syncthreads();

#pragma unroll 1
    for (int ch = 0; ch < NCH; ++ch) {
        const int g0  = ch * GC;
        const int buf = ch & 1;

        if (ch + 1 < NCH) LOAD_STAGE(g0 + GC)   // issue next chunk's globals early

#pragma unroll
        for (int g4 = 0; g4 < GC; g4 += 4) {
            const f32x4 wq = *(const f32x4*)&w2[g0 + g4];   // uniform -> s_load
            f32x4 b1v[4], bev[4];
#pragma unroll
            for (int j = 0; j < 4; ++j) {
                b1v[j] = *(const f32x4*)&sB[buf][tc + 16 * j][g4];
                bev[j] = *(const f32x4*)&sB[buf][tc + 16 * j][16 + g4];
            }
#pragma unroll
            for (int i = 0; i < 8; ++i) {
                const f32x4 a1 = *(const f32x4*)&sA[buf][tr + 16 * i][g4];
                const f32x4 ae = *(const f32x4*)&sA[buf][tr + 16 * i][16 + g4];
#pragma unroll
                for (int j = 0; j < 4; ++j) {
                    float d = acc[i][j];
                    d += __builtin_amdgcn_fmed3f(a1.x + b1v[j].x, ae.x * bev[j].x, wq.x);
                    d += __builtin_amdgcn_fmed3f(a1.y + b1v[j].y, ae.y * bev[j].y, wq.y);
                    d += __builtin_amdgcn_fmed3f(a1.z + b1v[j].z, ae.z * bev[j].z, wq.z);
                    d += __builtin_amdgcn_fmed3f(a1.w + b1v[j].w, ae.w * bev[j].w, wq.w);
                    acc[i][j] = d;
                }
            }
        }

        if (ch + 1 < NCH) WRITE_STAGE(buf ^ 1)
        __syncthreads();
    }
#undef LOAD_STAGE
#undef WRITE_STAGE

    const float w2sum = *w2sum_p;
    float rsv[4];
#pragma unroll
    for (int j = 0; j < 4; ++j) rsv[j] = brew[m0 + tc + 16 * j];

#pragma unroll
    for (int i = 0; i < 8; ++i) {
        float sw = 0.0f, swr = 0.0f;
#pragma unroll
        for (int j = 0; j < 4; ++j) {
            const float dist = fabsf(acc[i][j] - w2sum);
            const float w = 1.0f / (dist + 1e-4f);
            sw += w;
            swr = fmaf(w, rsv[j], swr);
        }
#pragma unroll
        for (int k = 1; k < 16; k <<= 1) {   // reduce over tc (low 4 lane bits)
            sw  += __shfl_xor(sw, k);
            swr += __shfl_xor(swr, k);
        }
        if (tc == 0) {
            const int n = n0 + tr + 16 * i;
            partials[((size_t)n * MT + mt) * 2 + 0] = sw;
            partials[((size_t)n * MT + mt) * 2 + 1] = swr;
        }
    }
}

// --- Kernel 3: reduce tile partials, divide ------------------------------------
__global__ __launch_bounds__(256) void finalize_kernel(
    const float* __restrict__ partials, float* __restrict__ out)
{
    const int n = blockIdx.x * 256 + threadIdx.x;
    if (n < NROWS) {
        float sw = 0.0f, swr = 0.0f;
#pragma unroll
        for (int t = 0; t < MT; ++t) {
            sw  += partials[((size_t)n * MT + t) * 2 + 0];
            swr += partials[((size_t)n * MT + t) * 2 + 1];
        }
        out[n] = swr / sw;
    }
}

extern "C" void kernel_launch(void* const* d_in, const int* in_sizes, int n_in,
                              void* d_out, int out_size, void* d_ws, size_t ws_size,
                              hipStream_t stream)
{
    const float* embeds       = (const float*)d_in[0];  // [2048,128]
    const float* base_embeds  = (const float*)d_in[1];  // [2048,128]
    const float* base_rewards = (const float*)d_in[2];  // [2048]
    const float* W1           = (const float*)d_in[3];  // [128,128] (in,out)
    const float* w2           = (const float*)d_in[4];  // [128,1]
    float* out = (float*)d_out;

    // ws: partials [2048*MT*2] | A1W | AEW | B1W | BE (each 2048*128) | w2sum[1]
    float* partials = (float*)d_ws;
    float* A1W = partials + (size_t)NROWS * MT * 2;
    float* AEW = A1W + (size_t)NROWS * F;
    float* B1W = AEW + (size_t)NROWS * F;
    float* BEp = B1W + (size_t)MROWS * F;
    float* w2s = BEp + (size_t)MROWS * F;

    proj_kernel<<<(NROWS + MROWS) / 2, 256, 0, stream>>>(
        embeds, base_embeds, W1, w2, A1W, AEW, B1W, BEp, w2s);

    dim3 grid2(NROWS / BN, MROWS / BM);
    pair_kernel<<<grid2, 256, 0, stream>>>(A1W, AEW, B1W, BEp, w2, w2s, base_rewards, partials);

    finalize_kernel<<<(NROWS + 255) / 256, 256, 0, stream>>>(partials, out);
}

// Round 8
// 74.942 us; speedup vs baseline: 3.4906x; 1.4944x over previous
//
#include <hip/hip_runtime.h>
#include <hip/hip_bf16.h>

#define F      128
#define NROWS  2048
#define MROWS  2048
#define BN     128         // n-rows per pair block
#define BM     64          // m-cols per pair block
#define MT     (MROWS/BM)  // 32 m-tiles
#define LOG2E  1.44269504088896340736f

typedef float f32x2 __attribute__((ext_vector_type(2)));
typedef float f32x4 __attribute__((ext_vector_type(4)));

__device__ __forceinline__ f32x2 lo2(f32x4 v) { return __builtin_shufflevector(v, v, 0, 1); }
__device__ __forceinline__ f32x2 hi2(f32x4 v) { return __builtin_shufflevector(v, v, 2, 3); }
__device__ __forceinline__ f32x2 pk_add(f32x2 a, f32x2 b) {
    f32x2 d; asm("v_pk_add_f32 %0, %1, %2" : "=v"(d) : "v"(a), "v"(b)); return d;
}
__device__ __forceinline__ f32x2 pk_mul(f32x2 a, f32x2 b) {
    f32x2 d; asm("v_pk_mul_f32 %0, %1, %2" : "=v"(d) : "v"(a), "v"(b)); return d;
}
// async global->LDS, 16B per lane; LDS dest = wave-uniform base + lane*16
__device__ __forceinline__ void gload16(const float* g, float* l) {
    __builtin_amdgcn_global_load_lds(
        (const __attribute__((address_space(1))) void*)g,
        (__attribute__((address_space(3))) void*)l, 16, 0, 0);
}

// --- Kernel 1: projections + ELU/w2 precompute + w2sum ----------------------
// a = (embeds@W1)[n][g], b = (base@W1)[m][g], w = w2[g]
// Fused-interleaved layout: P[row][ (g>>4)*32 + (g&15) ]      = plane0
//                           P[row][ (g>>4)*32 + 16 + (g&15) ] = plane1
// PA: p0 = (a+1)*w, p1 = exp(a)*w ;  PB: p0 = -b*w, p1 = exp(-b)
// Then w*elu(a-b) + w = med3(p0A + p0B, p1A * p1B, w).
__global__ __launch_bounds__(256) void proj_kernel(
    const float* __restrict__ embeds, const float* __restrict__ base,
    const float* __restrict__ W1, const float* __restrict__ w2,
    float* __restrict__ PA, float* __restrict__ PB,
    float* __restrict__ w2sum)
{
    const int tid = threadIdx.x;
    const int sub = tid >> 7;
    const int g   = tid & 127;
    const int row = blockIdx.x * 2 + sub;

    __shared__ float xs[2][F];
    {
        const float* src = (row < NROWS) ? &embeds[(size_t)row * F]
                                         : &base[(size_t)(row - NROWS) * F];
        xs[sub][g] = src[g];
    }
    __syncthreads();

    float acc = 0.0f;
#pragma unroll 8
    for (int f = 0; f < F; ++f)
        acc = fmaf(xs[sub][f], W1[f * F + g], acc);

    const float wv = w2[g];
    const int   ch = g >> 4, go = g & 15;
    if (row < NROWS) {
        float* dst = PA + (size_t)row * 256 + ch * 32 + go;
        dst[0]  = (acc + 1.0f) * wv;
        dst[16] = __builtin_amdgcn_exp2f(acc * LOG2E) * wv;
    } else {
        float* dst = PB + (size_t)(row - NROWS) * 256 + ch * 32 + go;
        dst[0]  = -acc * wv;
        dst[16] = __builtin_amdgcn_exp2f(-acc * LOG2E);
    }

    if (blockIdx.x == 0 && tid < 64) {
        float s = w2[tid] + w2[tid + 64];
#pragma unroll
        for (int k = 1; k < 64; k <<= 1) s += __shfl_xor(s, k);
        if (tid == 0) *w2sum = s;
    }
}

// --- Kernel 2: pair kernel ----------------------------------------------------
// grid (16,32), 256 threads; tile 128(n)x64(m); tr=tid>>4, tc=tid&15; Rn=8,Rm=4.
// LDS: linear 32-float rows, XOR-swizzled data (source pre-swizzled at stage,
// reads XOR by ((row&7)*4)); double-buffered via global_load_lds, 1 barrier/chunk.
__global__ __launch_bounds__(256, 3) void pair_kernel(
    const float* __restrict__ PA, const float* __restrict__ PB,
    const float* __restrict__ w2, const float* __restrict__ w2sum_p,
    const float* __restrict__ brew, float* __restrict__ partials)
{
    __shared__ float sbuf[2][6144];   // per buf: A rows 0..127 @ [0,4096), B rows @ [4096,6144)
    __shared__ float w2l[F];

    const int tid = threadIdx.x;
    const int w    = tid >> 6;        // wave 0..3
    const int l    = tid & 63;
    const int nt   = blockIdx.x, mt = blockIdx.y;
    const int n0   = nt * BN,    m0 = mt * BM;
    const int tr   = tid >> 4,   tc = tid & 15;
    const int fa   = (tr & 7) * 4,  fb = (tc & 7) * 4;
    const int rsub = l >> 3;
    const int lswz = 4 * ((l & 7) ^ rsub);   // pre-swizzled source col (floats)

    // 24 x 1KB blocks per chunk: k = t*4 + w ; k<16 -> A rows 8k..8k+7, else B.
#define STAGE(CH, BUF) {                                                        \
    const float* pa = PA + (size_t)(n0 + rsub) * 256 + (CH) * 32 + lswz;        \
    _Pragma("unroll")                                                           \
    for (int t = 0; t < 4; ++t) {                                               \
        const int k = t * 4 + w;                                                \
        gload16(pa + (size_t)(8 * k) * 256, &sbuf[BUF][k * 256]);               \
    }                                                                           \
    const float* pb = PB + (size_t)(m0 + rsub) * 256 + (CH) * 32 + lswz;        \
    _Pragma("unroll")                                                           \
    for (int t = 0; t < 2; ++t) {                                               \
        const int k = t * 4 + w;                                                \
        gload16(pb + (size_t)(8 * k) * 256, &sbuf[BUF][4096 + k * 256]);        \
    } }

    f32x2 acc2[8][2];   // acc2[i][jj] = (sum for j=2jj, sum for j=2jj+1)
#pragma unroll
    for (int i = 0; i < 8; ++i)
#pragma unroll
        for (int jj = 0; jj < 2; ++jj) acc2[i][jj] = (f32x2)(0.0f);

    STAGE(0, 0)
    if (tid < F) w2l[tid] = w2[tid];
    __syncthreads();

#pragma unroll 1
    for (int ch = 0; ch < 8; ++ch) {
        const int buf = ch & 1;
        if (ch < 7) STAGE(ch + 1, buf ^ 1);   // async into other buffer

        const float* sb = sbuf[buf];
#pragma unroll
        for (int g4 = 0; g4 < 16; g4 += 4) {
            const f32x4 wq = *(const f32x4*)&w2l[ch * 16 + g4];
            f32x4 b1v[4], bev[4];
#pragma unroll
            for (int j = 0; j < 4; ++j) {
                const float* bb = sb + 4096 + (tc + 16 * j) * 32;
                b1v[j] = *(const f32x4*)&bb[g4 ^ fb];
                bev[j] = *(const f32x4*)&bb[(16 + g4) ^ fb];
            }
#pragma unroll
            for (int i = 0; i < 8; ++i) {
                const float* ab = sb + (tr + 16 * i) * 32;
                const f32x4 a1 = *(const f32x4*)&ab[g4 ^ fa];
                const f32x4 ae = *(const f32x4*)&ab[(16 + g4) ^ fa];
                const f32x2 a1l = lo2(a1), a1h = hi2(a1);
                const f32x2 ael = lo2(ae), aeh = hi2(ae);
#pragma unroll
                for (int jj = 0; jj < 2; ++jj) {
                    const f32x2 xl0 = pk_add(a1l, lo2(b1v[2 * jj]));
                    const f32x2 xh0 = pk_add(a1h, hi2(b1v[2 * jj]));
                    const f32x2 el0 = pk_mul(ael, lo2(bev[2 * jj]));
                    const f32x2 eh0 = pk_mul(aeh, hi2(bev[2 * jj]));
                    const f32x2 xl1 = pk_add(a1l, lo2(b1v[2 * jj + 1]));
                    const f32x2 xh1 = pk_add(a1h, hi2(b1v[2 * jj + 1]));
                    const f32x2 el1 = pk_mul(ael, lo2(bev[2 * jj + 1]));
                    const f32x2 eh1 = pk_mul(aeh, hi2(bev[2 * jj + 1]));
                    f32x2 s0, s1, s2, s3;
                    s0.x = __builtin_amdgcn_fmed3f(xl0.x, el0.x, wq.x);
                    s0.y = __builtin_amdgcn_fmed3f(xl1.x, el1.x, wq.x);
                    s1.x = __builtin_amdgcn_fmed3f(xl0.y, el0.y, wq.y);
                    s1.y = __builtin_amdgcn_fmed3f(xl1.y, el1.y, wq.y);
                    s2.x = __builtin_amdgcn_fmed3f(xh0.x, eh0.x, wq.z);
                    s2.y = __builtin_amdgcn_fmed3f(xh1.x, eh1.x, wq.z);
                    s3.x = __builtin_amdgcn_fmed3f(xh0.y, eh0.y, wq.w);
                    s3.y = __builtin_amdgcn_fmed3f(xh1.y, eh1.y, wq.w);
                    f32x2 t = acc2[i][jj];
                    t = pk_add(t, s0);
                    t = pk_add(t, s1);
                    t = pk_add(t, s2);
                    t = pk_add(t, s3);
                    acc2[i][jj] = t;
                }
            }
        }
        __syncthreads();   // drains vmcnt (stage) + lgkm; buf^1 ready
    }
#undef STAGE

    const float w2sum = *w2sum_p;
    float rsv[4];
#pragma unroll
    for (int j = 0; j < 4; ++j) rsv[j] = brew[m0 + tc + 16 * j];

#pragma unroll
    for (int i = 0; i < 8; ++i) {
        float sw = 0.0f, swr = 0.0f;
#pragma unroll
        for (int j = 0; j < 4; ++j) {
            const float tot  = (j & 1) ? acc2[i][j >> 1].y : acc2[i][j >> 1].x;
            const float dist = fabsf(tot - w2sum);
            const float wgt  = 1.0f / (dist + 1e-4f);
            sw += wgt;
            swr = fmaf(wgt, rsv[j], swr);
        }
#pragma unroll
        for (int k = 1; k < 16; k <<= 1) {   // reduce over tc (low 4 lane bits)
            sw  += __shfl_xor(sw, k);
            swr += __shfl_xor(swr, k);
        }
        if (tc == 0) {
            const int n = n0 + tr + 16 * i;
            partials[((size_t)n * MT + mt) * 2 + 0] = sw;
            partials[((size_t)n * MT + mt) * 2 + 1] = swr;
        }
    }
}

// --- Kernel 3: reduce tile partials, divide ------------------------------------
__global__ __launch_bounds__(256) void finalize_kernel(
    const float* __restrict__ partials, float* __restrict__ out)
{
    const int n = blockIdx.x * 256 + threadIdx.x;
    if (n < NROWS) {
        float sw = 0.0f, swr = 0.0f;
#pragma unroll
        for (int t = 0; t < MT; ++t) {
            sw  += partials[((size_t)n * MT + t) * 2 + 0];
            swr += partials[((size_t)n * MT + t) * 2 + 1];
        }
        out[n] = swr / sw;
    }
}

extern "C" void kernel_launch(void* const* d_in, const int* in_sizes, int n_in,
                              void* d_out, int out_size, void* d_ws, size_t ws_size,
                              hipStream_t stream)
{
    const float* embeds       = (const float*)d_in[0];  // [2048,128]
    const float* base_embeds  = (const float*)d_in[1];  // [2048,128]
    const float* base_rewards = (const float*)d_in[2];  // [2048]
    const float* W1           = (const float*)d_in[3];  // [128,128] (in,out)
    const float* w2           = (const float*)d_in[4];  // [128,1]
    float* out = (float*)d_out;

    // ws: partials [2048*MT*2] | PA [2048*256] | PB [2048*256] | w2sum[1]
    float* partials = (float*)d_ws;
    float* PA  = partials + (size_t)NROWS * MT * 2;
    float* PB  = PA + (size_t)NROWS * 256;
    float* w2s = PB + (size_t)MROWS * 256;

    proj_kernel<<<(NROWS + MROWS) / 2, 256, 0, stream>>>(
        embeds, base_embeds, W1, w2, PA, PB, w2s);

    dim3 grid2(NROWS / BN, MROWS / BM);
    pair_kernel<<<grid2, 256, 0, stream>>>(PA, PB, w2, w2s, base_rewards, partials);

    finalize_kernel<<<(NROWS + 255) / 256, 256, 0, stream>>>(partials, out);
}